// Round 14
// baseline (178.969 us; speedup 1.0000x reference)
//
#include <hip/hip_runtime.h>

typedef unsigned short u16;
typedef unsigned int u32;
typedef short bf16x8 __attribute__((ext_vector_type(8)));
typedef float f32x4 __attribute__((ext_vector_type(4)));

#define CSC 0.18033688011112042f   // (1/8) * log2(e)

// ---------- bf16 helpers (RNE) ----------
__device__ __forceinline__ u16 f2bf(float f) {
    union { float f; unsigned u; } x; x.f = f;
    unsigned r = x.u + 0x7fffu + ((x.u >> 16) & 1u);
    return (u16)(r >> 16);
}
__device__ __forceinline__ float bf2f(u16 v) {
    union { unsigned u; float f; } x; x.u = ((unsigned)v) << 16;
    return x.f;
}
__device__ __forceinline__ u32 cvt_pk_bf16(float lo, float hi) {
    u32 r;
    asm("v_cvt_pk_bf16_f32 %0, %1, %2" : "=v"(r) : "v"(lo), "v"(hi));
    return r;
}
__device__ __forceinline__ float exp2_fast(float x) {
#if __has_builtin(__builtin_amdgcn_exp2f)
    return __builtin_amdgcn_exp2f(x);
#else
    return exp2f(x);
#endif
}
__device__ __forceinline__ void gl_lds16(const u16* g, u16* l) {
#if __has_builtin(__builtin_amdgcn_global_load_lds)
    __builtin_amdgcn_global_load_lds(
        (const __attribute__((address_space(1))) unsigned int*)g,
        (__attribute__((address_space(3))) unsigned int*)l, 16, 0, 0);
#else
    *(bf16x8*)l = *(const bf16x8*)g;
#endif
}
__device__ __forceinline__ int ileave(int x) {   // per-32 stored-key interleave
    return (x < 16) ? (x << 1) : (((x - 16) << 1) | 1);
}

// ---------- fp32 -> bf16 + RoPE cos/sin table, one launch ----------
// float4 index space: [0,1M) = x; then 4x 256K for wq,wk,wv,wo.
// Blocks >= 8192: fill tab[s][i] = (cos, sin)(s * 10000^(-i/32)),
// 2048 x 32 float2 = 512 KB (aliased onto the aob workspace region:
// written here -> read by gemm_qkv epilogue -> aob only written later
// by attn; stream-ordered, no race).
__global__ void cvt_all_kernel(const float* __restrict__ x, const float* __restrict__ wq,
                               const float* __restrict__ wk, const float* __restrict__ wv,
                               const float* __restrict__ wo,
                               u16* __restrict__ xb, u16* __restrict__ qkvw,
                               u16* __restrict__ ow, float2* __restrict__ tab) {
    int i = blockIdx.x * 256 + threadIdx.x;       // 0..2162687
    if (i >= 2097152) {
        int ti = i - 2097152;                     // 0..65535
        int s  = ti >> 5, pi = ti & 31;
        float inv = exp2_fast((float)pi * -0.4152410118609203f);  // 10000^(-pi/32)
        float ang = (float)s * inv;
        float sn, cs;
        sincosf(ang, &sn, &cs);
        tab[ti] = make_float2(cs, sn);
        return;
    }
    const float4* src;
    ushort4* dst;
    if (i < 1048576) {
        src = (const float4*)x + i;
        dst = (ushort4*)xb + i;
    } else {
        int r = i - 1048576;
        int m = r >> 18;
        int off = r & 262143;
        const float* s4 = (m == 0) ? wq : (m == 1) ? wk : (m == 2) ? wv : wo;
        u16* d = (m < 3) ? (qkvw + (size_t)m * 1048576) : ow;
        src = (const float4*)s4 + off;
        dst = (ushort4*)d + off;
    }
    float4 v = *src;
    ushort4 o;
    o.x = f2bf(v.x); o.y = f2bf(v.y); o.z = f2bf(v.z); o.w = f2bf(v.w);
    *dst = o;
}

// ---------- QKV GEMM: 128x128 tile, BK=32, C = A * Bw^T, N=3072 ----------
// R8 verified: dbuf single-barrier K-loop + both-sides chunk-XOR swizzle.
// RoPE fused in q/k epilogue; R14: angles from precomputed cos/sin TABLE
// (R13 post-mortem: 32 on-device sincosf/thread cost ~10us of VALU —
// Appendix B trig-table rule). Same f32 rotation + bf16 rounding path.
__global__ __launch_bounds__(256) void gemm_qkv(const u16* __restrict__ A,
                                                const u16* __restrict__ Bw,
                                                u16* __restrict__ C, int K,
                                                const float2* __restrict__ tab) {
    __shared__ __align__(16) u16 SB[16384];      // dbuf: [buf][As 4096 | Bs 4096]
    u16* SH = SB;                                // epilogue scratch alias
    const int tid  = threadIdx.x;
    const int bm   = blockIdx.x * 128;
    const int bn   = blockIdx.y * 128;
    const int wave = tid >> 6, lane = tid & 63;
    const int wm   = (wave >> 1) * 64, wn = (wave & 1) * 64;
    const int l16  = lane & 15, quad = lane >> 4;
    const int mat  = bn >> 10;                   // block-uniform (1024 % 128 == 0)

    f32x4 acc[4][4];
    #pragma unroll
    for (int i = 0; i < 4; i++)
        #pragma unroll
        for (int j = 0; j < 4; j++)
            #pragma unroll
            for (int e = 0; e < 4; e++) acc[i][j][e] = 0.0f;

    // stage-side source swizzle: LDS dest linear (row=tid>>2, chunk=tid&3),
    // global source chunk = (tid&3) ^ ((tid>>3)&3)   [(row>>1)&3]
    const int srow = tid >> 2;
    const int scol = (((tid & 3) ^ ((tid >> 3) & 3))) * 8;
    const u16* gA0 = A  + (size_t)(bm + srow) * K + scol;
    const u16* gA1 = A  + (size_t)(bm + 64 + srow) * K + scol;
    const u16* gB0 = Bw + (size_t)(bn + srow) * K + scol;
    const u16* gB1 = Bw + (size_t)(bn + 64 + srow) * K + scol;
    // read-side chunk swizzle (row = ..+l16, bases multiple of 16)
    const int csw = (quad ^ ((l16 >> 1) & 3)) * 8;

    auto stage = [&](int k0, int buf) {
        u16* As = SB + buf * 8192;
        u16* Bs = As + 4096;
        gl_lds16(gA0 + k0, As + (size_t)tid * 8);
        gl_lds16(gA1 + k0, As + (size_t)(tid + 256) * 8);
        gl_lds16(gB0 + k0, Bs + (size_t)tid * 8);
        gl_lds16(gB1 + k0, Bs + (size_t)(tid + 256) * 8);
    };

    stage(0, 0);
    int cur = 0;
    for (int k0 = 0; k0 < K; k0 += 32) {
        __syncthreads();             // drains vmcnt: SB[cur] ready, SB[cur^1] free
        if (k0 + 32 < K) stage(k0 + 32, cur ^ 1);
        const u16* As = SB + cur * 8192;
        const u16* Bs = As + 4096;
        bf16x8 af[4], bfr[4];
        #pragma unroll
        for (int i = 0; i < 4; i++) af[i]  = *(const bf16x8*)&As[(wm + i * 16 + l16) * 32 + csw];
        #pragma unroll
        for (int j = 0; j < 4; j++) bfr[j] = *(const bf16x8*)&Bs[(wn + j * 16 + l16) * 32 + csw];
        #pragma unroll
        for (int i = 0; i < 4; i++)
            #pragma unroll
            for (int j = 0; j < 4; j++)
                acc[i][j] = __builtin_amdgcn_mfma_f32_16x16x32_bf16(af[i], bfr[j], acc[i][j], 0, 0, 0);
        cur ^= 1;
    }

    const int b  = bm >> 11, sb = bm & 2047;     // tile-uniform (2048 % 128 == 0)
    if (mat < 2) {
        // q/k: LDS transpose SH[128][66-stride], rope (table) at write, 2 passes
        const float scale = (mat == 0) ? CSC : 1.0f;
        #pragma unroll
        for (int pass = 0; pass < 2; ++pass) {
            __syncthreads();
            if ((wn >> 6) == pass) {
                #pragma unroll
                for (int i = 0; i < 4; i++)
                    #pragma unroll
                    for (int j = 0; j < 4; j++)
                        #pragma unroll
                        for (int r = 0; r < 4; r++) {
                            int rl = wm + i * 16 + quad * 4 + r;   // 0..127
                            int cl = j * 16 + l16;                 // 0..63
                            SH[rl * 66 + cl] = f2bf(acc[i][j][r]);
                        }
            }
            __syncthreads();
            int rl   = tid >> 1;
            int half = (tid & 1) * 32;
            int c    = (bn + pass * 64) & 1023;                    // dv base 0, h fixed
            int h    = c >> 6;
            int s    = sb + rl;
            u16* dst = C + (size_t)mat * 4194304 +
                       (((size_t)(b * 16 + h) * 2048 + s) * 64) + half;
            const u16* srcp = &SH[rl * 66 + half];
            const float2* trow = tab + (size_t)s * 32 + (half >> 1);
            #pragma unroll
            for (int kk = 0; kk < 4; ++kk) {
                bf16x8 v = *(const bf16x8*)(srcp + kk * 8);
                bf16x8 ov;
                #pragma unroll
                for (int q = 0; q < 4; ++q) {
                    float2 cs2 = trow[kk * 4 + q];
                    float e  = bf2f(((u16*)&v)[2 * q]);
                    float od = bf2f(((u16*)&v)[2 * q + 1]);
                    ((u16*)&ov)[2 * q]     = f2bf((e * cs2.x - od * cs2.y) * scale);
                    ((u16*)&ov)[2 * q + 1] = f2bf((od * cs2.x + e * cs2.y) * scale);
                }
                *(bf16x8*)(dst + kk * 8) = ov;
            }
        }
    } else {
        // v^T: LDS transpose SH[64][130-stride] with stored-key interleave
        #pragma unroll
        for (int pass = 0; pass < 2; ++pass) {
            __syncthreads();
            if ((wn >> 6) == pass) {
                #pragma unroll
                for (int i = 0; i < 4; i++)
                    #pragma unroll
                    for (int j = 0; j < 4; j++)
                        #pragma unroll
                        for (int r = 0; r < 4; r++) {
                            int row = j * 16 + l16;                // 0..63 (dv local)
                            int ml  = wm + i * 16 + quad * 4 + r;  // 0..127 (key local)
                            int sp  = (ml & ~31) | ileave(ml & 31);
                            SH[row * 130 + sp] = f2bf(acc[i][j][r]);
                        }
            }
            __syncthreads();
            int row = tid >> 2, seg = tid & 3;
            int cc  = (bn + pass * 64 + row) & 1023;
            int h = cc >> 6, dv = cc & 63;
            u16* dst = C + (size_t)8388608 +
                       (((size_t)(b * 16 + h) * 64 + dv) * 2048) + sb + seg * 32;
            const u16* srcp = &SH[row * 130 + seg * 32];
            #pragma unroll
            for (int kk = 0; kk < 4; ++kk)
                *(bf16x8*)(dst + kk * 8) = *(const bf16x8*)(srcp + kk * 8);
        }
    }
}

// ---------- O-proj GEMM: 128x64 tile, BK=32, fp32 out [M,1024] ----------
// Same dbuf + both-sides swizzle transform as gemm_qkv.
__global__ __launch_bounds__(256, 2) void gemm_out(const u16* __restrict__ A,
                                                   const u16* __restrict__ Bw,
                                                   float* __restrict__ C, int K) {
    __shared__ __align__(16) u16 SB[12288];      // dbuf: [buf][As 4096 | Bs 2048]
    const int tid  = threadIdx.x;
    const int bm   = blockIdx.x * 128;
    const int bn   = blockIdx.y * 64;
    const int wave = tid >> 6, lane = tid & 63;
    const int wm   = wave * 32;
    const int l16  = lane & 15, quad = lane >> 4;

    f32x4 acc[2][4];
    #pragma unroll
    for (int i = 0; i < 2; i++)
        #pragma unroll
        for (int j = 0; j < 4; j++)
            #pragma unroll
            for (int e = 0; e < 4; e++) acc[i][j][e] = 0.0f;

    const int srow = tid >> 2;
    const int scol = (((tid & 3) ^ ((tid >> 3) & 3))) * 8;
    const u16* gA0 = A  + (size_t)(bm + srow) * K + scol;
    const u16* gA1 = A  + (size_t)(bm + 64 + srow) * K + scol;
    const u16* gB0 = Bw + (size_t)(bn + srow) * K + scol;
    const int csw = (quad ^ ((l16 >> 1) & 3)) * 8;

    auto stage = [&](int k0, int buf) {
        u16* base = SB + buf * 6144;
        gl_lds16(gA0 + k0, base + (size_t)tid * 8);
        gl_lds16(gA1 + k0, base + (size_t)(tid + 256) * 8);
        gl_lds16(gB0 + k0, base + 4096 + (size_t)tid * 8);
    };

    stage(0, 0);
    int cur = 0;
    for (int k0 = 0; k0 < K; k0 += 32) {
        __syncthreads();             // drains vmcnt: SB[cur] ready, SB[cur^1] free
        if (k0 + 32 < K) stage(k0 + 32, cur ^ 1);
        const u16* As = SB + cur * 6144;
        const u16* Bs = As + 4096;
        bf16x8 af[2], bfr[4];
        #pragma unroll
        for (int i = 0; i < 2; i++) af[i]  = *(const bf16x8*)&As[(wm + i * 16 + l16) * 32 + csw];
        #pragma unroll
        for (int j = 0; j < 4; j++) bfr[j] = *(const bf16x8*)&Bs[(j * 16 + l16) * 32 + csw];
        #pragma unroll
        for (int i = 0; i < 2; i++)
            #pragma unroll
            for (int j = 0; j < 4; j++)
                acc[i][j] = __builtin_amdgcn_mfma_f32_16x16x32_bf16(af[i], bfr[j], acc[i][j], 0, 0, 0);
        cur ^= 1;
    }

    #pragma unroll
    for (int i = 0; i < 2; i++)
        #pragma unroll
        for (int j = 0; j < 4; j++)
            #pragma unroll
            for (int r = 0; r < 4; r++) {
                int mr = bm + wm + i * 16 + quad * 4 + r;
                int nc = bn + j * 16 + l16;
                C[(size_t)mr * 1024 + nc] = acc[i][j][r];
            }
}

// ---------- Flash attention: 8-wave side-split (R11 best: 44.1us) + setprio ----------
// R12 post-mortem: fat 32-row waves regressed (58us) — R11's 8x16-row split
// restored verbatim. T5 s_setprio(1) around QK and PV MFMA clusters (R13:
// attn off top-5, kept). LDS = 32K KV dbuf + 8x1K P = 48KB -> 2 blocks/CU;
// (512,2) cap 128 VGPR. XCD swizzle bh=(bid&7)*4+(bid>>7); Q pre-scaled by
// CSC (fused rope); cvt_pk P-pack; chunk-XOR swizzles (bank-conflict = 0).
__global__ __launch_bounds__(512, 2) void attn_kernel(const u16* __restrict__ Q,
                                                      const u16* __restrict__ Kb,
                                                      const u16* __restrict__ Vt,
                                                      u16* __restrict__ Oout) {
    __shared__ __align__(16) u16 KV[2][8192];    // per buf: Klo|Khi|Vlo|Vhi, 2048 u16 each
    __shared__ __align__(16) u16 PW[8 * 1024];   // per wave: 16 rows x 32 u32 (swizzled)
    const int tid  = threadIdx.x;
    const int wave = tid >> 6, lane = tid & 63;
    const int side = wave >> 2;                  // 0 = B (full run), 1 = A (ends at t=j)
    const int wl   = wave & 3;
    const int l16  = lane & 15, quad = lane >> 4;
    const int bid  = blockIdx.x;
    const int j    = (bid >> 3) & 15;
    const int bh   = (bid & 7) * 4 + (bid >> 7);
    const int T    = 32 - j;                     // staged key tiles 0..T-1
    const int q0   = (side == 0 ? (31 - j) : j) * 64 + wl * 16;
    const int dTil = (side == 0) ? (T - 1) : j;  // this wave's diagonal tile

    const u16* Qh = Q  + (size_t)bh * 2048 * 64;
    const u16* Kh = Kb + (size_t)bh * 2048 * 64;
    const u16* Vh = Vt + (size_t)bh * 64 * 2048;

    bf16x8 qf0 = *(const bf16x8*)&Qh[(size_t)(q0 + l16) * 64 + quad * 8];
    bf16x8 qf1 = *(const bf16x8*)&Qh[(size_t)(q0 + l16) * 64 + 32 + quad * 8];

    f32x4 o[4];
    float ls[4];
    #pragma unroll
    for (int t = 0; t < 4; t++)
        #pragma unroll
        for (int e = 0; e < 4; e++) o[t][e] = 0.0f;
    #pragma unroll
    for (int r = 0; r < 4; r++) ls[r] = 0.0f;

    // staging: waves 0-3 load K (2 x gl_lds16), waves 4-7 load V.
    // source chunk swizzle c ^ ((row>>1)&3); LDS dest linear.
    const int tid2 = tid & 255;
    const int srow = tid2 >> 2;
    const int scs  = (((tid2 & 3) ^ ((tid2 >> 3) & 3))) * 8;
    const u16* gK = Kh + (size_t)srow * 64 + scs;
    const u16* gV = Vh + (size_t)srow * 2048 + scs;

    // read-side chunk swizzle for K/V fragment reads (u16 offset)
    const int cswz = (quad ^ ((l16 >> 1) & 3)) * 8;
    // read-side chunk swizzle for P reads (row = l16)
    const int psw0 = ((quad ^ (l16 & 7)) << 3);        // pf0: chunks 0..3
    const int psw1 = (((quad ^ (l16 & 7)) ^ 4) << 3);  // pf1: chunks 4..7

    u16* pw16 = PW + wave * 1024;
    u32* pw32 = (u32*)pw16;

    auto stage = [&](int t, int buf) {
        u16* base = KV[buf];
        if (tid < 256) {
            gl_lds16(gK + (size_t)t * 4096,      base + (size_t)tid2 * 8);
            gl_lds16(gK + (size_t)t * 4096 + 32, base + 2048 + (size_t)tid2 * 8);
        } else {
            gl_lds16(gV + (size_t)t * 64,        base + 4096 + (size_t)tid2 * 8);
            gl_lds16(gV + (size_t)t * 64 + 32,   base + 6144 + (size_t)tid2 * 8);
        }
    };

    stage(0, 0);
    for (int t = 0; t < T; ++t) {
        __syncthreads();              // drains vmcnt: buf[t&1] ready; buf[(t+1)&1] free
        if (t + 1 < T) stage(t + 1, (t + 1) & 1);
        const bool act = (side == 0) || (t <= j);
        if (act) {
            const u16* B = KV[t & 1];
            bf16x8 kf0[4], kf1[4], vf0[4], vf1[4];
            #pragma unroll
            for (int n = 0; n < 4; n++) {
                int ri = (n * 16 + l16) * 32 + cswz;
                kf0[n] = *(const bf16x8*)&B[ri];
                kf1[n] = *(const bf16x8*)&B[2048 + ri];
                vf0[n] = *(const bf16x8*)&B[4096 + ri];
                vf1[n] = *(const bf16x8*)&B[6144 + ri];
            }
            const int kbase = t * 64;
            const bool diag = (t == dTil);

            f32x4 s[4];
            __builtin_amdgcn_s_setprio(1);
            #pragma unroll
            for (int n = 0; n < 4; n++) {
                #pragma unroll
                for (int e = 0; e < 4; e++) s[n][e] = 0.0f;
                s[n] = __builtin_amdgcn_mfma_f32_16x16x32_bf16(qf0, kf0[n], s[n], 0, 0, 0);
                s[n] = __builtin_amdgcn_mfma_f32_16x16x32_bf16(qf1, kf1[n], s[n], 0, 0, 0);
            }
            __builtin_amdgcn_s_setprio(0);
            float p[4][4];
            #pragma unroll
            for (int n = 0; n < 4; n++)
                #pragma unroll
                for (int r = 0; r < 4; r++) {
                    float v = exp2_fast(s[n][r]);    // q pre-scaled: s already *CSC
                    if (diag) {
                        int row = q0 + quad * 4 + r;
                        v = (kbase + n * 16 + l16 > row) ? 0.0f : v;
                    }
                    p[n][r] = v;
                    ls[r] += v;
                }
            #pragma unroll
            for (int c = 0; c < 2; c++)
                #pragma unroll
                for (int r = 0; r < 4; r++) {
                    int prow = quad * 4 + r;
                    int pj   = (((c * 4 + (l16 >> 2)) ^ (prow & 7)) << 2) | (l16 & 3);
                    pw32[prow * 32 + pj] = cvt_pk_bf16(p[2 * c][r], p[2 * c + 1][r]);
                }
            asm volatile("s_waitcnt lgkmcnt(0)" ::: "memory");   // wave-local drain
            bf16x8 pf0 = *(const bf16x8*)&pw16[l16 * 64 + psw0];
            bf16x8 pf1 = *(const bf16x8*)&pw16[l16 * 64 + psw1];
            __builtin_amdgcn_s_setprio(1);
            #pragma unroll
            for (int dn = 0; dn < 4; dn++) {
                o[dn] = __builtin_amdgcn_mfma_f32_16x16x32_bf16(pf0, vf0[dn], o[dn], 0, 0, 0);
                o[dn] = __builtin_amdgcn_mfma_f32_16x16x32_bf16(pf1, vf1[dn], o[dn], 0, 0, 0);
            }
            __builtin_amdgcn_s_setprio(0);
        }
    }

    #pragma unroll
    for (int off = 1; off < 16; off <<= 1)
        #pragma unroll
        for (int r = 0; r < 4; r++)
            ls[r] += __shfl_xor(ls[r], off);

    const int b = bh >> 4, h = bh & 15;
    #pragma unroll
    for (int r = 0; r < 4; r++) {
        float inv = 1.0f / ls[r];
        int srw = q0 + quad * 4 + r;
        #pragma unroll
        for (int dn = 0; dn < 4; dn++) {
            int d = h * 64 + dn * 16 + l16;
            Oout[((size_t)b * 2048 + srw) * 1024 + d] = f2bf(o[dn][r] * inv);
        }
    }
}

extern "C" void kernel_launch(void* const* d_in, const int* in_sizes, int n_in,
                              void* d_out, int out_size, void* d_ws, size_t ws_size,
                              hipStream_t stream) {
    const float* x  = (const float*)d_in[0];
    const float* wq = (const float*)d_in[1];
    const float* wk = (const float*)d_in[2];
    const float* wv = (const float*)d_in[3];
    const float* wo = (const float*)d_in[4];
    float* out = (float*)d_out;

    const int M = 4096, D = 1024;
    u16* xb    = (u16*)d_ws;                      // [4096,1024]            8 MB
    u16* qkvw  = xb   + (size_t)M * D;            // wq|wk|wv bf16          6 MB
    u16* ow    = qkvw + (size_t)3 * D * D;        // wo bf16                2 MB
    u16* qkv   = ow   + (size_t)D * D;            // q | k | v^T            24 MB
    u16* qb    = qkv;
    u16* kb    = qkv + (size_t)M * D;
    u16* vtb   = qkv + (size_t)2 * M * D;
    u16* aob   = qkv + (size_t)3 * M * D;         // attn out bf16 [B,S,D]  8 MB
    float2* tab = (float2*)aob;                   // 512 KB rope table, aliased:
                                                  // cvt writes -> gemm_qkv reads
                                                  // -> attn overwrites aob later

    cvt_all_kernel<<<8448, 256, 0, stream>>>(x, wq, wk, wv, wo, xb, qkvw, ow, tab);

    dim3 gq(32, 24);                               // 768 blocks = 3/CU; rope fused (table)
    gemm_qkv<<<gq, 256, 0, stream>>>(xb, qkvw, qkv, D, tab);

    attn_kernel<<<512, 512, 0, stream>>>(qb, kb, vtb, aob);

    dim3 go(32, 16);                               // 512 blocks, 128x64 tiles
    gemm_out<<<go, 256, 0, stream>>>(aob, ow, out, D);
}

// Round 15
// 178.103 us; speedup vs baseline: 1.0049x; 1.0049x over previous
//
#include <hip/hip_runtime.h>

typedef unsigned short u16;
typedef unsigned int u32;
typedef short bf16x8 __attribute__((ext_vector_type(8)));
typedef float f32x4 __attribute__((ext_vector_type(4)));

#define CSC 0.18033688011112042f   // (1/8) * log2(e)

// ---------- bf16 helpers (RNE) ----------
__device__ __forceinline__ u16 f2bf(float f) {
    union { float f; unsigned u; } x; x.f = f;
    unsigned r = x.u + 0x7fffu + ((x.u >> 16) & 1u);
    return (u16)(r >> 16);
}
__device__ __forceinline__ float bf2f(u16 v) {
    union { unsigned u; float f; } x; x.u = ((unsigned)v) << 16;
    return x.f;
}
__device__ __forceinline__ u32 cvt_pk_bf16(float lo, float hi) {
    u32 r;
    asm("v_cvt_pk_bf16_f32 %0, %1, %2" : "=v"(r) : "v"(lo), "v"(hi));
    return r;
}
__device__ __forceinline__ float exp2_fast(float x) {
#if __has_builtin(__builtin_amdgcn_exp2f)
    return __builtin_amdgcn_exp2f(x);
#else
    return exp2f(x);
#endif
}
__device__ __forceinline__ void gl_lds16(const u16* g, u16* l) {
#if __has_builtin(__builtin_amdgcn_global_load_lds)
    __builtin_amdgcn_global_load_lds(
        (const __attribute__((address_space(1))) unsigned int*)g,
        (__attribute__((address_space(3))) unsigned int*)l, 16, 0, 0);
#else
    *(bf16x8*)l = *(const bf16x8*)g;
#endif
}
__device__ __forceinline__ int ileave(int x) {   // per-32 stored-key interleave
    return (x < 16) ? (x << 1) : (((x - 16) << 1) | 1);
}

// ---------- fp32 -> bf16, all inputs in one launch ----------
// float4 index space: [0,1M) = x; then 4x 256K for wq,wk,wv,wo.
__global__ void cvt_all_kernel(const float* __restrict__ x, const float* __restrict__ wq,
                               const float* __restrict__ wk, const float* __restrict__ wv,
                               const float* __restrict__ wo,
                               u16* __restrict__ xb, u16* __restrict__ qkvw,
                               u16* __restrict__ ow) {
    int i = blockIdx.x * 256 + threadIdx.x;       // 0..2097151
    const float4* src;
    ushort4* dst;
    if (i < 1048576) {
        src = (const float4*)x + i;
        dst = (ushort4*)xb + i;
    } else {
        int r = i - 1048576;
        int m = r >> 18;
        int off = r & 262143;
        const float* s4 = (m == 0) ? wq : (m == 1) ? wk : (m == 2) ? wv : wo;
        u16* d = (m < 3) ? (qkvw + (size_t)m * 1048576) : ow;
        src = (const float4*)s4 + off;
        dst = (ushort4*)d + off;
    }
    float4 v = *src;
    ushort4 o;
    o.x = f2bf(v.x); o.y = f2bf(v.y); o.z = f2bf(v.z); o.w = f2bf(v.w);
    *dst = o;
}

// ---------- RoPE in-place, vectorized b128; q additionally pre-scaled by CSC ----------
// R15: restored as a separate kernel. R12-R14 measured all three rope
// placements (separate / fused-trig / fused-table) e2e-equal (~179); the
// separate kernel is the simplest and keeps gemm_qkv at its R8-clean form.
__global__ void rope_kernel(u16* __restrict__ qb, u16* __restrict__ kb) {
    int idx = blockIdx.x * 256 + threadIdx.x;     // chunk of 8 u16; 524288 per buffer
    u16* buf;
    float scale;
    if (blockIdx.y == 0) { buf = qb; scale = CSC; } else { buf = kb; scale = 1.0f; }
    int g   = idx & 7;
    int row = idx >> 3;                           // bh*2048 + s
    int s   = row & 2047;
    u16* p = buf + (size_t)row * 64 + g * 8;
    bf16x8 v = *(bf16x8*)p;
    bf16x8 o;
    #pragma unroll
    for (int q = 0; q < 4; ++q) {
        int i = g * 4 + q;                        // pair index 0..31
        float inv = exp2_fast((float)i * -0.4152410118609203f);   // 10000^(-i/32)
        float ang = (float)s * inv;
        float sn, cs;
        sincosf(ang, &sn, &cs);
        float e  = bf2f(((u16*)&v)[2 * q]);
        float od = bf2f(((u16*)&v)[2 * q + 1]);
        ((u16*)&o)[2 * q]     = f2bf((e * cs - od * sn) * scale);
        ((u16*)&o)[2 * q + 1] = f2bf((od * cs + e * sn) * scale);
    }
    *(bf16x8*)p = o;
}

// ---------- QKV GEMM: 128x128 tile, BK=32, C = A * Bw^T, N=3072 ----------
// R8 verified form: dbuf single-barrier K-loop + both-sides chunk-XOR
// swizzle (bank conflicts 3.47M -> ~0). Plain epilogues (no rope).
__global__ __launch_bounds__(256) void gemm_qkv(const u16* __restrict__ A,
                                                const u16* __restrict__ Bw,
                                                u16* __restrict__ C, int K) {
    __shared__ __align__(16) u16 SB[16384];      // dbuf: [buf][As 4096 | Bs 4096]
    u16* SH = SB;                                // epilogue scratch alias
    const int tid  = threadIdx.x;
    const int bm   = blockIdx.x * 128;
    const int bn   = blockIdx.y * 128;
    const int wave = tid >> 6, lane = tid & 63;
    const int wm   = (wave >> 1) * 64, wn = (wave & 1) * 64;
    const int l16  = lane & 15, quad = lane >> 4;
    const int mat  = bn >> 10;                   // block-uniform (1024 % 128 == 0)

    f32x4 acc[4][4];
    #pragma unroll
    for (int i = 0; i < 4; i++)
        #pragma unroll
        for (int j = 0; j < 4; j++)
            #pragma unroll
            for (int e = 0; e < 4; e++) acc[i][j][e] = 0.0f;

    // stage-side source swizzle: LDS dest linear (row=tid>>2, chunk=tid&3),
    // global source chunk = (tid&3) ^ ((tid>>3)&3)   [(row>>1)&3]
    const int srow = tid >> 2;
    const int scol = (((tid & 3) ^ ((tid >> 3) & 3))) * 8;
    const u16* gA0 = A  + (size_t)(bm + srow) * K + scol;
    const u16* gA1 = A  + (size_t)(bm + 64 + srow) * K + scol;
    const u16* gB0 = Bw + (size_t)(bn + srow) * K + scol;
    const u16* gB1 = Bw + (size_t)(bn + 64 + srow) * K + scol;
    // read-side chunk swizzle (row = ..+l16, bases multiple of 16)
    const int csw = (quad ^ ((l16 >> 1) & 3)) * 8;

    auto stage = [&](int k0, int buf) {
        u16* As = SB + buf * 8192;
        u16* Bs = As + 4096;
        gl_lds16(gA0 + k0, As + (size_t)tid * 8);
        gl_lds16(gA1 + k0, As + (size_t)(tid + 256) * 8);
        gl_lds16(gB0 + k0, Bs + (size_t)tid * 8);
        gl_lds16(gB1 + k0, Bs + (size_t)(tid + 256) * 8);
    };

    stage(0, 0);
    int cur = 0;
    for (int k0 = 0; k0 < K; k0 += 32) {
        __syncthreads();             // drains vmcnt: SB[cur] ready, SB[cur^1] free
        if (k0 + 32 < K) stage(k0 + 32, cur ^ 1);
        const u16* As = SB + cur * 8192;
        const u16* Bs = As + 4096;
        bf16x8 af[4], bfr[4];
        #pragma unroll
        for (int i = 0; i < 4; i++) af[i]  = *(const bf16x8*)&As[(wm + i * 16 + l16) * 32 + csw];
        #pragma unroll
        for (int j = 0; j < 4; j++) bfr[j] = *(const bf16x8*)&Bs[(wn + j * 16 + l16) * 32 + csw];
        #pragma unroll
        for (int i = 0; i < 4; i++)
            #pragma unroll
            for (int j = 0; j < 4; j++)
                acc[i][j] = __builtin_amdgcn_mfma_f32_16x16x32_bf16(af[i], bfr[j], acc[i][j], 0, 0, 0);
        cur ^= 1;
    }

    const int b  = bm >> 11, sb = bm & 2047;     // tile-uniform (2048 % 128 == 0)
    if (mat < 2) {
        // q/k: LDS transpose SH[128][66-stride], b128 stores, 2 passes of 64 cols
        #pragma unroll
        for (int pass = 0; pass < 2; ++pass) {
            __syncthreads();
            if ((wn >> 6) == pass) {
                #pragma unroll
                for (int i = 0; i < 4; i++)
                    #pragma unroll
                    for (int j = 0; j < 4; j++)
                        #pragma unroll
                        for (int r = 0; r < 4; r++) {
                            int rl = wm + i * 16 + quad * 4 + r;   // 0..127
                            int cl = j * 16 + l16;                 // 0..63
                            SH[rl * 66 + cl] = f2bf(acc[i][j][r]);
                        }
            }
            __syncthreads();
            int rl   = tid >> 1;
            int half = (tid & 1) * 32;
            int c    = (bn + pass * 64) & 1023;                    // dv base 0, h fixed
            int h    = c >> 6;
            int s    = sb + rl;
            u16* dst = C + (size_t)mat * 4194304 +
                       (((size_t)(b * 16 + h) * 2048 + s) * 64) + half;
            const u16* srcp = &SH[rl * 66 + half];
            #pragma unroll
            for (int kk = 0; kk < 4; ++kk)
                *(bf16x8*)(dst + kk * 8) = *(const bf16x8*)(srcp + kk * 8);
        }
    } else {
        // v^T: LDS transpose SH[64][130-stride] with stored-key interleave
        #pragma unroll
        for (int pass = 0; pass < 2; ++pass) {
            __syncthreads();
            if ((wn >> 6) == pass) {
                #pragma unroll
                for (int i = 0; i < 4; i++)
                    #pragma unroll
                    for (int j = 0; j < 4; j++)
                        #pragma unroll
                        for (int r = 0; r < 4; r++) {
                            int row = j * 16 + l16;                // 0..63 (dv local)
                            int ml  = wm + i * 16 + quad * 4 + r;  // 0..127 (key local)
                            int sp  = (ml & ~31) | ileave(ml & 31);
                            SH[row * 130 + sp] = f2bf(acc[i][j][r]);
                        }
            }
            __syncthreads();
            int row = tid >> 2, seg = tid & 3;
            int cc  = (bn + pass * 64 + row) & 1023;
            int h = cc >> 6, dv = cc & 63;
            u16* dst = C + (size_t)8388608 +
                       (((size_t)(b * 16 + h) * 64 + dv) * 2048) + sb + seg * 32;
            const u16* srcp = &SH[row * 130 + seg * 32];
            #pragma unroll
            for (int kk = 0; kk < 4; ++kk)
                *(bf16x8*)(dst + kk * 8) = *(const bf16x8*)(srcp + kk * 8);
        }
    }
}

// ---------- O-proj GEMM: 128x64 tile, BK=64, fp32 out [M,1024] ----------
// R15: BK 32->64 (halves barrier+stage rounds: 32 -> 16; m97-analysis puts
// the per-barrier vmcnt drain at ~20% of such loops) + full 8-chunk XOR
// swizzle (BK=64 rows = 128 B: unswizzled, ALL rows alias one bank group —
// worse than BK=32; chunk ^= row&7 makes fragment reads 2-way = free).
// LDS = 2 buf x (As 16K + Bs 8K) = 48 KB -> 2 blocks/CU unchanged.
__global__ __launch_bounds__(256, 2) void gemm_out(const u16* __restrict__ A,
                                                   const u16* __restrict__ Bw,
                                                   float* __restrict__ C, int K) {
    __shared__ __align__(16) u16 SB[24576];      // dbuf: [buf][As 8192 | Bs 4096]
    const int tid  = threadIdx.x;
    const int bm   = blockIdx.x * 128;
    const int bn   = blockIdx.y * 64;
    const int wave = tid >> 6, lane = tid & 63;
    const int wm   = wave * 32;
    const int l16  = lane & 15, quad = lane >> 4;

    f32x4 acc[2][4];
    #pragma unroll
    for (int i = 0; i < 2; i++)
        #pragma unroll
        for (int j = 0; j < 4; j++)
            #pragma unroll
            for (int e = 0; e < 4; e++) acc[i][j][e] = 0.0f;

    // staging: slot s = l*256+tid -> row = l*32 + (tid>>3), chunk = tid&7.
    // global source chunk = (tid&7) ^ (row&7) = (tid&7) ^ ((tid>>3)&7)
    // (l*32 == 0 mod 8). LDS dest linear at slot*8.
    const int srowS = tid >> 3;                   // 0..31
    const int scol8 = (((tid & 7) ^ ((tid >> 3) & 7))) * 8;
    const u16* gA = A  + (size_t)(bm + srowS) * K + scol8;
    const u16* gB = Bw + (size_t)(bn + srowS) * K + scol8;
    // read-side chunk swizzle: chunk(kk,quad) ^ (row&7); row&7 == l16&7
    const int rsw = (l16 & 7);

    auto stage = [&](int k0, int buf) {
        u16* As = SB + buf * 12288;
        u16* Bs = As + 8192;
        #pragma unroll
        for (int l = 0; l < 4; ++l)
            gl_lds16(gA + (size_t)(l * 32) * K + k0, As + (size_t)(l * 256 + tid) * 8);
        #pragma unroll
        for (int l = 0; l < 2; ++l)
            gl_lds16(gB + (size_t)(l * 32) * K + k0, Bs + (size_t)(l * 256 + tid) * 8);
    };

    stage(0, 0);
    int cur = 0;
    for (int k0 = 0; k0 < K; k0 += 64) {
        __syncthreads();             // drains vmcnt: SB[cur] ready, SB[cur^1] free
        if (k0 + 64 < K) stage(k0 + 64, cur ^ 1);
        const u16* As = SB + cur * 12288;
        const u16* Bs = As + 8192;
        #pragma unroll
        for (int kk = 0; kk < 2; ++kk) {
            const int ch = ((kk * 4 + quad) ^ rsw) * 8;
            bf16x8 af[2], bfr[4];
            #pragma unroll
            for (int i = 0; i < 2; i++) af[i]  = *(const bf16x8*)&As[(wm + i * 16 + l16) * 64 + ch];
            #pragma unroll
            for (int j = 0; j < 4; j++) bfr[j] = *(const bf16x8*)&Bs[(j * 16 + l16) * 64 + ch];
            #pragma unroll
            for (int i = 0; i < 2; i++)
                #pragma unroll
                for (int j = 0; j < 4; j++)
                    acc[i][j] = __builtin_amdgcn_mfma_f32_16x16x32_bf16(af[i], bfr[j], acc[i][j], 0, 0, 0);
        }
        cur ^= 1;
    }

    #pragma unroll
    for (int i = 0; i < 2; i++)
        #pragma unroll
        for (int j = 0; j < 4; j++)
            #pragma unroll
            for (int r = 0; r < 4; r++) {
                int mr = bm + wm + i * 16 + quad * 4 + r;
                int nc = bn + j * 16 + l16;
                C[(size_t)mr * 1024 + nc] = acc[i][j][r];
            }
}

// ---------- Flash attention: 8-wave side-split (R11 best: 44.1us) + setprio ----------
// R12 post-mortem: fat 32-row waves regressed (58us) — R11's 8x16-row split
// kept. T5 s_setprio(1) around QK and PV MFMA clusters.
// LDS = 32K KV dbuf + 8x1K P = 48KB -> 2 blocks/CU; (512,2) cap 128 VGPR.
// XCD swizzle bh=(bid&7)*4+(bid>>7); Q pre-scaled by CSC (rope kernel);
// cvt_pk P-pack; K/V + P chunk-XOR swizzles (bank-conflict = 0).
__global__ __launch_bounds__(512, 2) void attn_kernel(const u16* __restrict__ Q,
                                                      const u16* __restrict__ Kb,
                                                      const u16* __restrict__ Vt,
                                                      u16* __restrict__ Oout) {
    __shared__ __align__(16) u16 KV[2][8192];    // per buf: Klo|Khi|Vlo|Vhi, 2048 u16 each
    __shared__ __align__(16) u16 PW[8 * 1024];   // per wave: 16 rows x 32 u32 (swizzled)
    const int tid  = threadIdx.x;
    const int wave = tid >> 6, lane = tid & 63;
    const int side = wave >> 2;                  // 0 = B (full run), 1 = A (ends at t=j)
    const int wl   = wave & 3;
    const int l16  = lane & 15, quad = lane >> 4;
    const int bid  = blockIdx.x;
    const int j    = (bid >> 3) & 15;
    const int bh   = (bid & 7) * 4 + (bid >> 7);
    const int T    = 32 - j;                     // staged key tiles 0..T-1
    const int q0   = (side == 0 ? (31 - j) : j) * 64 + wl * 16;
    const int dTil = (side == 0) ? (T - 1) : j;  // this wave's diagonal tile

    const u16* Qh = Q  + (size_t)bh * 2048 * 64;
    const u16* Kh = Kb + (size_t)bh * 2048 * 64;
    const u16* Vh = Vt + (size_t)bh * 64 * 2048;

    bf16x8 qf0 = *(const bf16x8*)&Qh[(size_t)(q0 + l16) * 64 + quad * 8];
    bf16x8 qf1 = *(const bf16x8*)&Qh[(size_t)(q0 + l16) * 64 + 32 + quad * 8];

    f32x4 o[4];
    float ls[4];
    #pragma unroll
    for (int t = 0; t < 4; t++)
        #pragma unroll
        for (int e = 0; e < 4; e++) o[t][e] = 0.0f;
    #pragma unroll
    for (int r = 0; r < 4; r++) ls[r] = 0.0f;

    // staging: waves 0-3 load K (2 x gl_lds16), waves 4-7 load V.
    // source chunk swizzle c ^ ((row>>1)&3); LDS dest linear.
    const int tid2 = tid & 255;
    const int srow = tid2 >> 2;
    const int scs  = (((tid2 & 3) ^ ((tid2 >> 3) & 3))) * 8;
    const u16* gK = Kh + (size_t)srow * 64 + scs;
    const u16* gV = Vh + (size_t)srow * 2048 + scs;

    // read-side chunk swizzle for K/V fragment reads (u16 offset)
    const int cswz = (quad ^ ((l16 >> 1) & 3)) * 8;
    // read-side chunk swizzle for P reads (row = l16)
    const int psw0 = ((quad ^ (l16 & 7)) << 3);        // pf0: chunks 0..3
    const int psw1 = (((quad ^ (l16 & 7)) ^ 4) << 3);  // pf1: chunks 4..7

    u16* pw16 = PW + wave * 1024;
    u32* pw32 = (u32*)pw16;

    auto stage = [&](int t, int buf) {
        u16* base = KV[buf];
        if (tid < 256) {
            gl_lds16(gK + (size_t)t * 4096,      base + (size_t)tid2 * 8);
            gl_lds16(gK + (size_t)t * 4096 + 32, base + 2048 + (size_t)tid2 * 8);
        } else {
            gl_lds16(gV + (size_t)t * 64,        base + 4096 + (size_t)tid2 * 8);
            gl_lds16(gV + (size_t)t * 64 + 32,   base + 6144 + (size_t)tid2 * 8);
        }
    };

    stage(0, 0);
    for (int t = 0; t < T; ++t) {
        __syncthreads();              // drains vmcnt: buf[t&1] ready; buf[(t+1)&1] free
        if (t + 1 < T) stage(t + 1, (t + 1) & 1);
        const bool act = (side == 0) || (t <= j);
        if (act) {
            const u16* B = KV[t & 1];
            bf16x8 kf0[4], kf1[4], vf0[4], vf1[4];
            #pragma unroll
            for (int n = 0; n < 4; n++) {
                int ri = (n * 16 + l16) * 32 + cswz;
                kf0[n] = *(const bf16x8*)&B[ri];
                kf1[n] = *(const bf16x8*)&B[2048 + ri];
                vf0[n] = *(const bf16x8*)&B[4096 + ri];
                vf1[n] = *(const bf16x8*)&B[6144 + ri];
            }
            const int kbase = t * 64;
            const bool diag = (t == dTil);

            f32x4 s[4];
            __builtin_amdgcn_s_setprio(1);
            #pragma unroll
            for (int n = 0; n < 4; n++) {
                #pragma unroll
                for (int e = 0; e < 4; e++) s[n][e] = 0.0f;
                s[n] = __builtin_amdgcn_mfma_f32_16x16x32_bf16(qf0, kf0[n], s[n], 0, 0, 0);
                s[n] = __builtin_amdgcn_mfma_f32_16x16x32_bf16(qf1, kf1[n], s[n], 0, 0, 0);
            }
            __builtin_amdgcn_s_setprio(0);
            float p[4][4];
            #pragma unroll
            for (int n = 0; n < 4; n++)
                #pragma unroll
                for (int r = 0; r < 4; r++) {
                    float v = exp2_fast(s[n][r]);    // q pre-scaled: s already *CSC
                    if (diag) {
                        int row = q0 + quad * 4 + r;
                        v = (kbase + n * 16 + l16 > row) ? 0.0f : v;
                    }
                    p[n][r] = v;
                    ls[r] += v;
                }
            #pragma unroll
            for (int c = 0; c < 2; c++)
                #pragma unroll
                for (int r = 0; r < 4; r++) {
                    int prow = quad * 4 + r;
                    int pj   = (((c * 4 + (l16 >> 2)) ^ (prow & 7)) << 2) | (l16 & 3);
                    pw32[prow * 32 + pj] = cvt_pk_bf16(p[2 * c][r], p[2 * c + 1][r]);
                }
            asm volatile("s_waitcnt lgkmcnt(0)" ::: "memory");   // wave-local drain
            bf16x8 pf0 = *(const bf16x8*)&pw16[l16 * 64 + psw0];
            bf16x8 pf1 = *(const bf16x8*)&pw16[l16 * 64 + psw1];
            __builtin_amdgcn_s_setprio(1);
            #pragma unroll
            for (int dn = 0; dn < 4; dn++) {
                o[dn] = __builtin_amdgcn_mfma_f32_16x16x32_bf16(pf0, vf0[dn], o[dn], 0, 0, 0);
                o[dn] = __builtin_amdgcn_mfma_f32_16x16x32_bf16(pf1, vf1[dn], o[dn], 0, 0, 0);
            }
            __builtin_amdgcn_s_setprio(0);
        }
    }

    #pragma unroll
    for (int off = 1; off < 16; off <<= 1)
        #pragma unroll
        for (int r = 0; r < 4; r++)
            ls[r] += __shfl_xor(ls[r], off);

    const int b = bh >> 4, h = bh & 15;
    #pragma unroll
    for (int r = 0; r < 4; r++) {
        float inv = 1.0f / ls[r];
        int srw = q0 + quad * 4 + r;
        #pragma unroll
        for (int dn = 0; dn < 4; dn++) {
            int d = h * 64 + dn * 16 + l16;
            Oout[((size_t)b * 2048 + srw) * 1024 + d] = f2bf(o[dn][r] * inv);
        }
    }
}

extern "C" void kernel_launch(void* const* d_in, const int* in_sizes, int n_in,
                              void* d_out, int out_size, void* d_ws, size_t ws_size,
                              hipStream_t stream) {
    const float* x  = (const float*)d_in[0];
    const float* wq = (const float*)d_in[1];
    const float* wk = (const float*)d_in[2];
    const float* wv = (const float*)d_in[3];
    const float* wo = (const float*)d_in[4];
    float* out = (float*)d_out;

    const int M = 4096, D = 1024;
    u16* xb    = (u16*)d_ws;                      // [4096,1024]            8 MB
    u16* qkvw  = xb   + (size_t)M * D;            // wq|wk|wv bf16          6 MB
    u16* ow    = qkvw + (size_t)3 * D * D;        // wo bf16                2 MB
    u16* qkv   = ow   + (size_t)D * D;            // q | k | v^T            24 MB
    u16* qb    = qkv;
    u16* kb    = qkv + (size_t)M * D;
    u16* vtb   = qkv + (size_t)2 * M * D;
    u16* aob   = qkv + (size_t)3 * M * D;         // attn out bf16 [B,S,D]  8 MB

    cvt_all_kernel<<<8192, 256, 0, stream>>>(x, wq, wk, wv, wo, xb, qkvw, ow);

    dim3 gq(32, 24);                               // 768 blocks = 3/CU
    gemm_qkv<<<gq, 256, 0, stream>>>(xb, qkvw, qkv, D);

    dim3 gr(2048, 2);                              // b128 rope; q pre-scaled by CSC
    rope_kernel<<<gr, 256, 0, stream>>>(qb, kb);

    attn_kernel<<<512, 512, 0, stream>>>(qb, kb, vtb, aob);

    dim3 go(32, 16);                               // 512 blocks, 128x64 tiles, BK=64
    gemm_out<<<go, 256, 0, stream>>>(aob, ow, out, D);
}

// Round 16
// 176.411 us; speedup vs baseline: 1.0145x; 1.0096x over previous
//
#include <hip/hip_runtime.h>

typedef unsigned short u16;
typedef unsigned int u32;
typedef short bf16x8 __attribute__((ext_vector_type(8)));
typedef float f32x4 __attribute__((ext_vector_type(4)));

#define CSC 0.18033688011112042f   // (1/8) * log2(e)

// ---------- bf16 helpers (RNE) ----------
__device__ __forceinline__ u16 f2bf(float f) {
    union { float f; unsigned u; } x; x.f = f;
    unsigned r = x.u + 0x7fffu + ((x.u >> 16) & 1u);
    return (u16)(r >> 16);
}
__device__ __forceinline__ float bf2f(u16 v) {
    union { unsigned u; float f; } x; x.u = ((unsigned)v) << 16;
    return x.f;
}
__device__ __forceinline__ u32 cvt_pk_bf16(float lo, float hi) {
    u32 r;
    asm("v_cvt_pk_bf16_f32 %0, %1, %2" : "=v"(r) : "v"(lo), "v"(hi));
    return r;
}
__device__ __forceinline__ float exp2_fast(float x) {
#if __has_builtin(__builtin_amdgcn_exp2f)
    return __builtin_amdgcn_exp2f(x);
#else
    return exp2f(x);
#endif
}
__device__ __forceinline__ void gl_lds16(const u16* g, u16* l) {
#if __has_builtin(__builtin_amdgcn_global_load_lds)
    __builtin_amdgcn_global_load_lds(
        (const __attribute__((address_space(1))) unsigned int*)g,
        (__attribute__((address_space(3))) unsigned int*)l, 16, 0, 0);
#else
    *(bf16x8*)l = *(const bf16x8*)g;
#endif
}
__device__ __forceinline__ int ileave(int x) {   // per-32 stored-key interleave
    return (x < 16) ? (x << 1) : (((x - 16) << 1) | 1);
}

// ---------- fp32 -> bf16, all inputs in one launch ----------
// float4 index space: [0,1M) = x; then 4x 256K for wq,wk,wv,wo.
__global__ void cvt_all_kernel(const float* __restrict__ x, const float* __restrict__ wq,
                               const float* __restrict__ wk, const float* __restrict__ wv,
                               const float* __restrict__ wo,
                               u16* __restrict__ xb, u16* __restrict__ qkvw,
                               u16* __restrict__ ow) {
    int i = blockIdx.x * 256 + threadIdx.x;       // 0..2097151
    const float4* src;
    ushort4* dst;
    if (i < 1048576) {
        src = (const float4*)x + i;
        dst = (ushort4*)xb + i;
    } else {
        int r = i - 1048576;
        int m = r >> 18;
        int off = r & 262143;
        const float* s4 = (m == 0) ? wq : (m == 1) ? wk : (m == 2) ? wv : wo;
        u16* d = (m < 3) ? (qkvw + (size_t)m * 1048576) : ow;
        src = (const float4*)s4 + off;
        dst = (ushort4*)d + off;
    }
    float4 v = *src;
    ushort4 o;
    o.x = f2bf(v.x); o.y = f2bf(v.y); o.z = f2bf(v.z); o.w = f2bf(v.w);
    *dst = o;
}

// ---------- RoPE in-place, vectorized b128; q additionally pre-scaled by CSC ----------
__global__ void rope_kernel(u16* __restrict__ qb, u16* __restrict__ kb) {
    int idx = blockIdx.x * 256 + threadIdx.x;     // chunk of 8 u16; 524288 per buffer
    u16* buf;
    float scale;
    if (blockIdx.y == 0) { buf = qb; scale = CSC; } else { buf = kb; scale = 1.0f; }
    int g   = idx & 7;
    int row = idx >> 3;                           // bh*2048 + s
    int s   = row & 2047;
    u16* p = buf + (size_t)row * 64 + g * 8;
    bf16x8 v = *(bf16x8*)p;
    bf16x8 o;
    #pragma unroll
    for (int q = 0; q < 4; ++q) {
        int i = g * 4 + q;                        // pair index 0..31
        float inv = exp2_fast((float)i * -0.4152410118609203f);   // 10000^(-i/32)
        float ang = (float)s * inv;
        float sn, cs;
        sincosf(ang, &sn, &cs);
        float e  = bf2f(((u16*)&v)[2 * q]);
        float od = bf2f(((u16*)&v)[2 * q + 1]);
        ((u16*)&o)[2 * q]     = f2bf((e * cs - od * sn) * scale);
        ((u16*)&o)[2 * q + 1] = f2bf((od * cs + e * sn) * scale);
    }
    *(bf16x8*)p = o;
}

// ---------- QKV GEMM: 128x128 tile, BK=32, C = A * Bw^T, N=3072 ----------
// R8 verified form: dbuf single-barrier K-loop + both-sides chunk-XOR
// swizzle (bank conflicts 3.47M -> ~0). Plain epilogues (no rope).
__global__ __launch_bounds__(256) void gemm_qkv(const u16* __restrict__ A,
                                                const u16* __restrict__ Bw,
                                                u16* __restrict__ C, int K) {
    __shared__ __align__(16) u16 SB[16384];      // dbuf: [buf][As 4096 | Bs 4096]
    u16* SH = SB;                                // epilogue scratch alias
    const int tid  = threadIdx.x;
    const int bm   = blockIdx.x * 128;
    const int bn   = blockIdx.y * 128;
    const int wave = tid >> 6, lane = tid & 63;
    const int wm   = (wave >> 1) * 64, wn = (wave & 1) * 64;
    const int l16  = lane & 15, quad = lane >> 4;
    const int mat  = bn >> 10;                   // block-uniform (1024 % 128 == 0)

    f32x4 acc[4][4];
    #pragma unroll
    for (int i = 0; i < 4; i++)
        #pragma unroll
        for (int j = 0; j < 4; j++)
            #pragma unroll
            for (int e = 0; e < 4; e++) acc[i][j][e] = 0.0f;

    // stage-side source swizzle: LDS dest linear (row=tid>>2, chunk=tid&3),
    // global source chunk = (tid&3) ^ ((tid>>3)&3)   [(row>>1)&3]
    const int srow = tid >> 2;
    const int scol = (((tid & 3) ^ ((tid >> 3) & 3))) * 8;
    const u16* gA0 = A  + (size_t)(bm + srow) * K + scol;
    const u16* gA1 = A  + (size_t)(bm + 64 + srow) * K + scol;
    const u16* gB0 = Bw + (size_t)(bn + srow) * K + scol;
    const u16* gB1 = Bw + (size_t)(bn + 64 + srow) * K + scol;
    // read-side chunk swizzle (row = ..+l16, bases multiple of 16)
    const int csw = (quad ^ ((l16 >> 1) & 3)) * 8;

    auto stage = [&](int k0, int buf) {
        u16* As = SB + buf * 8192;
        u16* Bs = As + 4096;
        gl_lds16(gA0 + k0, As + (size_t)tid * 8);
        gl_lds16(gA1 + k0, As + (size_t)(tid + 256) * 8);
        gl_lds16(gB0 + k0, Bs + (size_t)tid * 8);
        gl_lds16(gB1 + k0, Bs + (size_t)(tid + 256) * 8);
    };

    stage(0, 0);
    int cur = 0;
    for (int k0 = 0; k0 < K; k0 += 32) {
        __syncthreads();             // drains vmcnt: SB[cur] ready, SB[cur^1] free
        if (k0 + 32 < K) stage(k0 + 32, cur ^ 1);
        const u16* As = SB + cur * 8192;
        const u16* Bs = As + 4096;
        bf16x8 af[4], bfr[4];
        #pragma unroll
        for (int i = 0; i < 4; i++) af[i]  = *(const bf16x8*)&As[(wm + i * 16 + l16) * 32 + csw];
        #pragma unroll
        for (int j = 0; j < 4; j++) bfr[j] = *(const bf16x8*)&Bs[(wn + j * 16 + l16) * 32 + csw];
        #pragma unroll
        for (int i = 0; i < 4; i++)
            #pragma unroll
            for (int j = 0; j < 4; j++)
                acc[i][j] = __builtin_amdgcn_mfma_f32_16x16x32_bf16(af[i], bfr[j], acc[i][j], 0, 0, 0);
        cur ^= 1;
    }

    const int b  = bm >> 11, sb = bm & 2047;     // tile-uniform (2048 % 128 == 0)
    if (mat < 2) {
        // q/k: LDS transpose SH[128][66-stride], b128 stores, 2 passes of 64 cols
        #pragma unroll
        for (int pass = 0; pass < 2; ++pass) {
            __syncthreads();
            if ((wn >> 6) == pass) {
                #pragma unroll
                for (int i = 0; i < 4; i++)
                    #pragma unroll
                    for (int j = 0; j < 4; j++)
                        #pragma unroll
                        for (int r = 0; r < 4; r++) {
                            int rl = wm + i * 16 + quad * 4 + r;   // 0..127
                            int cl = j * 16 + l16;                 // 0..63
                            SH[rl * 66 + cl] = f2bf(acc[i][j][r]);
                        }
            }
            __syncthreads();
            int rl   = tid >> 1;
            int half = (tid & 1) * 32;
            int c    = (bn + pass * 64) & 1023;                    // dv base 0, h fixed
            int h    = c >> 6;
            int s    = sb + rl;
            u16* dst = C + (size_t)mat * 4194304 +
                       (((size_t)(b * 16 + h) * 2048 + s) * 64) + half;
            const u16* srcp = &SH[rl * 66 + half];
            #pragma unroll
            for (int kk = 0; kk < 4; ++kk)
                *(bf16x8*)(dst + kk * 8) = *(const bf16x8*)(srcp + kk * 8);
        }
    } else {
        // v^T: LDS transpose SH[64][130-stride] with stored-key interleave
        #pragma unroll
        for (int pass = 0; pass < 2; ++pass) {
            __syncthreads();
            if ((wn >> 6) == pass) {
                #pragma unroll
                for (int i = 0; i < 4; i++)
                    #pragma unroll
                    for (int j = 0; j < 4; j++)
                        #pragma unroll
                        for (int r = 0; r < 4; r++) {
                            int row = j * 16 + l16;                // 0..63 (dv local)
                            int ml  = wm + i * 16 + quad * 4 + r;  // 0..127 (key local)
                            int sp  = (ml & ~31) | ileave(ml & 31);
                            SH[row * 130 + sp] = f2bf(acc[i][j][r]);
                        }
            }
            __syncthreads();
            int row = tid >> 2, seg = tid & 3;
            int cc  = (bn + pass * 64 + row) & 1023;
            int h = cc >> 6, dv = cc & 63;
            u16* dst = C + (size_t)8388608 +
                       (((size_t)(b * 16 + h) * 64 + dv) * 2048) + sb + seg * 32;
            const u16* srcp = &SH[row * 130 + seg * 32];
            #pragma unroll
            for (int kk = 0; kk < 4; ++kk)
                *(bf16x8*)(dst + kk * 8) = *(const bf16x8*)(srcp + kk * 8);
        }
    }
}

// ---------- O-proj GEMM: 128x64 tile, BK=64, fp32 out [M,1024] ----------
// R16: epilogue routed through LDS (float SH[128][68], aliased onto the
// freed staging buffer) -> 16-lanes-per-row float4 stores = 256B fully
// coalesced segments. Replaces 32 scattered global_store_dword/thread
// (the suspected reason gemm_out never left the ~45-55us range: 16MB of
// ~64B-granular fp32 writes). K-loop unchanged from R15 (BK=64, 8-chunk
// XOR swizzle, dbuf single-barrier). LDS 48KB -> 2 blocks/CU.
__global__ __launch_bounds__(256, 2) void gemm_out(const u16* __restrict__ A,
                                                   const u16* __restrict__ Bw,
                                                   float* __restrict__ C, int K) {
    __shared__ __align__(16) u16 SB[24576];      // dbuf: [buf][As 8192 | Bs 4096]
    const int tid  = threadIdx.x;
    const int bm   = blockIdx.x * 128;
    const int bn   = blockIdx.y * 64;
    const int wave = tid >> 6, lane = tid & 63;
    const int wm   = wave * 32;
    const int l16  = lane & 15, quad = lane >> 4;

    f32x4 acc[2][4];
    #pragma unroll
    for (int i = 0; i < 2; i++)
        #pragma unroll
        for (int j = 0; j < 4; j++)
            #pragma unroll
            for (int e = 0; e < 4; e++) acc[i][j][e] = 0.0f;

    // staging: slot s = l*256+tid -> row = l*32 + (tid>>3), chunk = tid&7.
    // global source chunk = (tid&7) ^ (row&7) = (tid&7) ^ ((tid>>3)&7)
    // (l*32 == 0 mod 8). LDS dest linear at slot*8.
    const int srowS = tid >> 3;                   // 0..31
    const int scol8 = (((tid & 7) ^ ((tid >> 3) & 7))) * 8;
    const u16* gA = A  + (size_t)(bm + srowS) * K + scol8;
    const u16* gB = Bw + (size_t)(bn + srowS) * K + scol8;
    // read-side chunk swizzle: chunk(kk,quad) ^ (row&7); row&7 == l16&7
    const int rsw = (l16 & 7);

    auto stage = [&](int k0, int buf) {
        u16* As = SB + buf * 12288;
        u16* Bs = As + 8192;
        #pragma unroll
        for (int l = 0; l < 4; ++l)
            gl_lds16(gA + (size_t)(l * 32) * K + k0, As + (size_t)(l * 256 + tid) * 8);
        #pragma unroll
        for (int l = 0; l < 2; ++l)
            gl_lds16(gB + (size_t)(l * 32) * K + k0, Bs + (size_t)(l * 256 + tid) * 8);
    };

    stage(0, 0);
    int cur = 0;
    for (int k0 = 0; k0 < K; k0 += 64) {
        __syncthreads();             // drains vmcnt: SB[cur] ready, SB[cur^1] free
        if (k0 + 64 < K) stage(k0 + 64, cur ^ 1);
        const u16* As = SB + cur * 12288;
        const u16* Bs = As + 8192;
        #pragma unroll
        for (int kk = 0; kk < 2; ++kk) {
            const int ch = ((kk * 4 + quad) ^ rsw) * 8;
            bf16x8 af[2], bfr[4];
            #pragma unroll
            for (int i = 0; i < 2; i++) af[i]  = *(const bf16x8*)&As[(wm + i * 16 + l16) * 64 + ch];
            #pragma unroll
            for (int j = 0; j < 4; j++) bfr[j] = *(const bf16x8*)&Bs[(j * 16 + l16) * 64 + ch];
            #pragma unroll
            for (int i = 0; i < 2; i++)
                #pragma unroll
                for (int j = 0; j < 4; j++)
                    acc[i][j] = __builtin_amdgcn_mfma_f32_16x16x32_bf16(af[i], bfr[j], acc[i][j], 0, 0, 0);
        }
        cur ^= 1;
    }

    // ---- epilogue: LDS transpose (float SH[128][68]) + coalesced float4 stores ----
    __syncthreads();                 // all waves done reading SB before overwrite
    float* SHf = (float*)SB;         // 128*68*4 = 34816 B <= 49152 B
    #pragma unroll
    for (int i = 0; i < 2; i++)
        #pragma unroll
        for (int j = 0; j < 4; j++)
            #pragma unroll
            for (int r = 0; r < 4; r++)
                SHf[(wm + i * 16 + quad * 4 + r) * 68 + j * 16 + l16] = acc[i][j][r];
    __syncthreads();
    const int rl = tid >> 4;          // 0..15
    const int c4 = (tid & 15) * 4;    // 0..60
    #pragma unroll
    for (int rr = 0; rr < 8; ++rr) {
        int row = rr * 16 + rl;
        float4 v = *(const float4*)&SHf[row * 68 + c4];
        *(float4*)&C[(size_t)(bm + row) * 1024 + bn + c4] = v;
    }
}

// ---------- Flash attention: 8-wave side-split (R11 best: 44.1us) + setprio ----------
// LDS = 32K KV dbuf + 8x1K P = 48KB -> 2 blocks/CU; (512,2) cap 128 VGPR.
// XCD swizzle bh=(bid&7)*4+(bid>>7); Q pre-scaled by CSC (rope kernel);
// cvt_pk P-pack; K/V + P chunk-XOR swizzles (bank-conflict = 0).
__global__ __launch_bounds__(512, 2) void attn_kernel(const u16* __restrict__ Q,
                                                      const u16* __restrict__ Kb,
                                                      const u16* __restrict__ Vt,
                                                      u16* __restrict__ Oout) {
    __shared__ __align__(16) u16 KV[2][8192];    // per buf: Klo|Khi|Vlo|Vhi, 2048 u16 each
    __shared__ __align__(16) u16 PW[8 * 1024];   // per wave: 16 rows x 32 u32 (swizzled)
    const int tid  = threadIdx.x;
    const int wave = tid >> 6, lane = tid & 63;
    const int side = wave >> 2;                  // 0 = B (full run), 1 = A (ends at t=j)
    const int wl   = wave & 3;
    const int l16  = lane & 15, quad = lane >> 4;
    const int bid  = blockIdx.x;
    const int j    = (bid >> 3) & 15;
    const int bh   = (bid & 7) * 4 + (bid >> 7);
    const int T    = 32 - j;                     // staged key tiles 0..T-1
    const int q0   = (side == 0 ? (31 - j) : j) * 64 + wl * 16;
    const int dTil = (side == 0) ? (T - 1) : j;  // this wave's diagonal tile

    const u16* Qh = Q  + (size_t)bh * 2048 * 64;
    const u16* Kh = Kb + (size_t)bh * 2048 * 64;
    const u16* Vh = Vt + (size_t)bh * 64 * 2048;

    bf16x8 qf0 = *(const bf16x8*)&Qh[(size_t)(q0 + l16) * 64 + quad * 8];
    bf16x8 qf1 = *(const bf16x8*)&Qh[(size_t)(q0 + l16) * 64 + 32 + quad * 8];

    f32x4 o[4];
    float ls[4];
    #pragma unroll
    for (int t = 0; t < 4; t++)
        #pragma unroll
        for (int e = 0; e < 4; e++) o[t][e] = 0.0f;
    #pragma unroll
    for (int r = 0; r < 4; r++) ls[r] = 0.0f;

    // staging: waves 0-3 load K (2 x gl_lds16), waves 4-7 load V.
    // source chunk swizzle c ^ ((row>>1)&3); LDS dest linear.
    const int tid2 = tid & 255;
    const int srow = tid2 >> 2;
    const int scs  = (((tid2 & 3) ^ ((tid2 >> 3) & 3))) * 8;
    const u16* gK = Kh + (size_t)srow * 64 + scs;
    const u16* gV = Vh + (size_t)srow * 2048 + scs;

    // read-side chunk swizzle for K/V fragment reads (u16 offset)
    const int cswz = (quad ^ ((l16 >> 1) & 3)) * 8;
    // read-side chunk swizzle for P reads (row = l16)
    const int psw0 = ((quad ^ (l16 & 7)) << 3);        // pf0: chunks 0..3
    const int psw1 = (((quad ^ (l16 & 7)) ^ 4) << 3);  // pf1: chunks 4..7

    u16* pw16 = PW + wave * 1024;
    u32* pw32 = (u32*)pw16;

    auto stage = [&](int t, int buf) {
        u16* base = KV[buf];
        if (tid < 256) {
            gl_lds16(gK + (size_t)t * 4096,      base + (size_t)tid2 * 8);
            gl_lds16(gK + (size_t)t * 4096 + 32, base + 2048 + (size_t)tid2 * 8);
        } else {
            gl_lds16(gV + (size_t)t * 64,        base + 4096 + (size_t)tid2 * 8);
            gl_lds16(gV + (size_t)t * 64 + 32,   base + 6144 + (size_t)tid2 * 8);
        }
    };

    stage(0, 0);
    for (int t = 0; t < T; ++t) {
        __syncthreads();              // drains vmcnt: buf[t&1] ready; buf[(t+1)&1] free
        if (t + 1 < T) stage(t + 1, (t + 1) & 1);
        const bool act = (side == 0) || (t <= j);
        if (act) {
            const u16* B = KV[t & 1];
            bf16x8 kf0[4], kf1[4], vf0[4], vf1[4];
            #pragma unroll
            for (int n = 0; n < 4; n++) {
                int ri = (n * 16 + l16) * 32 + cswz;
                kf0[n] = *(const bf16x8*)&B[ri];
                kf1[n] = *(const bf16x8*)&B[2048 + ri];
                vf0[n] = *(const bf16x8*)&B[4096 + ri];
                vf1[n] = *(const bf16x8*)&B[6144 + ri];
            }
            const int kbase = t * 64;
            const bool diag = (t == dTil);

            f32x4 s[4];
            __builtin_amdgcn_s_setprio(1);
            #pragma unroll
            for (int n = 0; n < 4; n++) {
                #pragma unroll
                for (int e = 0; e < 4; e++) s[n][e] = 0.0f;
                s[n] = __builtin_amdgcn_mfma_f32_16x16x32_bf16(qf0, kf0[n], s[n], 0, 0, 0);
                s[n] = __builtin_amdgcn_mfma_f32_16x16x32_bf16(qf1, kf1[n], s[n], 0, 0, 0);
            }
            __builtin_amdgcn_s_setprio(0);
            float p[4][4];
            #pragma unroll
            for (int n = 0; n < 4; n++)
                #pragma unroll
                for (int r = 0; r < 4; r++) {
                    float v = exp2_fast(s[n][r]);    // q pre-scaled: s already *CSC
                    if (diag) {
                        int row = q0 + quad * 4 + r;
                        v = (kbase + n * 16 + l16 > row) ? 0.0f : v;
                    }
                    p[n][r] = v;
                    ls[r] += v;
                }
            #pragma unroll
            for (int c = 0; c < 2; c++)
                #pragma unroll
                for (int r = 0; r < 4; r++) {
                    int prow = quad * 4 + r;
                    int pj   = (((c * 4 + (l16 >> 2)) ^ (prow & 7)) << 2) | (l16 & 3);
                    pw32[prow * 32 + pj] = cvt_pk_bf16(p[2 * c][r], p[2 * c + 1][r]);
                }
            asm volatile("s_waitcnt lgkmcnt(0)" ::: "memory");   // wave-local drain
            bf16x8 pf0 = *(const bf16x8*)&pw16[l16 * 64 + psw0];
            bf16x8 pf1 = *(const bf16x8*)&pw16[l16 * 64 + psw1];
            __builtin_amdgcn_s_setprio(1);
            #pragma unroll
            for (int dn = 0; dn < 4; dn++) {
                o[dn] = __builtin_amdgcn_mfma_f32_16x16x32_bf16(pf0, vf0[dn], o[dn], 0, 0, 0);
                o[dn] = __builtin_amdgcn_mfma_f32_16x16x32_bf16(pf1, vf1[dn], o[dn], 0, 0, 0);
            }
            __builtin_amdgcn_s_setprio(0);
        }
    }

    #pragma unroll
    for (int off = 1; off < 16; off <<= 1)
        #pragma unroll
        for (int r = 0; r < 4; r++)
            ls[r] += __shfl_xor(ls[r], off);

    const int b = bh >> 4, h = bh & 15;
    #pragma unroll
    for (int r = 0; r < 4; r++) {
        float inv = 1.0f / ls[r];
        int srw = q0 + quad * 4 + r;
        #pragma unroll
        for (int dn = 0; dn < 4; dn++) {
            int d = h * 64 + dn * 16 + l16;
            Oout[((size_t)b * 2048 + srw) * 1024 + d] = f2bf(o[dn][r] * inv);
        }
    }
}

extern "C" void kernel_launch(void* const* d_in, const int* in_sizes, int n_in,
                              void* d_out, int out_size, void* d_ws, size_t ws_size,
                              hipStream_t stream) {
    const float* x  = (const float*)d_in[0];
    const float* wq = (const float*)d_in[1];
    const float* wk = (const float*)d_in[2];
    const float* wv = (const float*)d_in[3];
    const float* wo = (const float*)d_in[4];
    float* out = (float*)d_out;

    const int M = 4096, D = 1024;
    u16* xb    = (u16*)d_ws;                      // [4096,1024]            8 MB
    u16* qkvw  = xb   + (size_t)M * D;            // wq|wk|wv bf16          6 MB
    u16* ow    = qkvw + (size_t)3 * D * D;        // wo bf16                2 MB
    u16* qkv   = ow   + (size_t)D * D;            // q | k | v^T            24 MB
    u16* qb    = qkv;
    u16* kb    = qkv + (size_t)M * D;
    u16* vtb   = qkv + (size_t)2 * M * D;
    u16* aob   = qkv + (size_t)3 * M * D;         // attn out bf16 [B,S,D]  8 MB

    cvt_all_kernel<<<8192, 256, 0, stream>>>(x, wq, wk, wv, wo, xb, qkvw, ow);

    dim3 gq(32, 24);                               // 768 blocks = 3/CU
    gemm_qkv<<<gq, 256, 0, stream>>>(xb, qkvw, qkv, D);

    dim3 gr(2048, 2);                              // b128 rope; q pre-scaled by CSC
    rope_kernel<<<gr, 256, 0, stream>>>(qb, kb);

    attn_kernel<<<512, 512, 0, stream>>>(qb, kb, vtb, aob);

    dim3 go(32, 16);                               // 512 blocks, 128x64 tiles, BK=64
    gemm_out<<<go, 256, 0, stream>>>(aob, ow, out, D);
}